// Round 11
// baseline (2474.323 us; speedup 1.0000x reference)
//
#include <hip/hip_runtime.h>
#include <math.h>

#define BB 32      // batch
#define NP 49      // spatial positions 7*7
#define FE 512     // FEAT
#define HI 512     // HID
#define EM 512     // emb dim
#define TT 60      // timesteps
#define G4 2048    // 4*HID
#define NV 10000   // vocab
#define ND 14      // disease dim
#define NBLK 80    // cooperative scan blocks: 64 gate + 16 a
#define NPAIR (BB*NP)   // 1568

typedef __attribute__((ext_vector_type(8))) short short8v;
typedef __attribute__((ext_vector_type(4))) float float4v;

__device__ __forceinline__ float fsig(float x){ return 1.0f/(1.0f+__expf(-x)); }
__device__ __forceinline__ float ftanh(float x){
    x = fminf(fmaxf(x, -15.0f), 15.0f);
    float e = __expf(2.0f*x);
    return (e-1.0f)/(e+1.0f);
}
__device__ __forceinline__ ushort f2bf(float x){
    union { float f; unsigned u; } v; v.f = x;
    unsigned r = v.u + 0x7fff + ((v.u >> 16) & 1);
    return (ushort)(r >> 16);
}
__device__ __forceinline__ float bf2f(ushort h){
    union { float f; unsigned u; } v; v.u = ((unsigned)h) << 16;
    return v.f;
}
__device__ __forceinline__ ushort f2bf_trunc(float x){
    return (ushort)(__float_as_uint(x) >> 16);
}

// features (B,512,49) -> fT (B,49,512)
__global__ void k_transpose(const float* __restrict__ feat, float* __restrict__ fT){
    int b = blockIdx.y;
    int cb = blockIdx.x * 64;
    __shared__ float tile[64][NP+1];
    const float* src = feat + (size_t)b*FE*NP;
    for (int idx = threadIdx.x; idx < 64*NP; idx += 256){
        int cl = idx / NP, n = idx % NP;
        tile[cl][n] = src[(size_t)(cb+cl)*NP + n];
    }
    __syncthreads();
    float* dst = fT + (size_t)b*NP*FE;
    for (int idx = threadIdx.x; idx < 64*NP; idx += 256){
        int cl = idx % 64, n = idx / 64;
        dst[(size_t)n*FE + cb + cl] = tile[cl][n];
    }
}

// per-batch disease MLPs + folded projections
__global__ void k_disease(const float* __restrict__ dis,
                          const float* __restrict__ Wdp1, const float* __restrict__ bdp1,
                          const float* __restrict__ Wdp2, const float* __restrict__ bdp2,
                          const float* __restrict__ Wde1, const float* __restrict__ bde1,
                          const float* __restrict__ Wde2, const float* __restrict__ bde2,
                          const float* __restrict__ Wattn, const float* __restrict__ battn,
                          const float* __restrict__ Wih, const float* __restrict__ bih,
                          const float* __restrict__ bhh,
                          float* __restrict__ daw, float* __restrict__ disWih){
    int b = blockIdx.x;
    int tid = threadIdx.x;
    __shared__ float d[ND];
    __shared__ float hp[128], he[128];
    __shared__ float datt[HI];
    __shared__ float dctx[256];
    if (tid < ND) d[tid] = dis[b*ND + tid];
    __syncthreads();
    if (tid < 128){
        float accP = bdp1[tid], accE = bde1[tid];
        for (int k=0;k<ND;k++){ accP += d[k]*Wdp1[k*128+tid]; accE += d[k]*Wde1[k*128+tid]; }
        hp[tid] = fmaxf(accP, 0.f);
        he[tid] = fmaxf(accE, 0.f);
    }
    __syncthreads();
    for (int j = tid; j < HI; j += 256){
        float a = bdp2[j];
        for (int k=0;k<128;k++) a += hp[k]*Wdp2[k*HI+j];
        datt[j] = a;
    }
    if (tid < 256){
        float a = bde2[tid];
        for (int k=0;k<128;k++) a += he[k]*Wde2[k*256+tid];
        dctx[tid] = a;
    }
    __syncthreads();
    for (int j = tid; j < HI; j += 256){
        float a = battn[j];
        for (int k=0;k<HI;k++) a += datt[k]*Wattn[(size_t)(FE+k)*HI + j];
        daw[b*HI + j] = a;
    }
    for (int j = tid; j < G4; j += 256){
        float a = bih[j] + bhh[j];
        for (int k=0;k<256;k++) a += dctx[k]*Wih[(size_t)(EM+FE+k)*G4 + j];
        disWih[b*G4 + j] = a;
    }
}

// f_projB[bkA][p][c]: blocked layout, bkA = col-block (j>>5), p = b*49+n, c = j&31
__global__ void k_fproj(const float* __restrict__ fT, const float* __restrict__ Wattn,
                        float* __restrict__ f_projB){
    int b = blockIdx.y, ng = blockIdx.x;
    int n0 = ng*7;
    __shared__ float fr[7][FE];
    const float* src = fT + ((size_t)b*NP + n0)*FE;
    for (int idx = threadIdx.x; idx < 7*FE; idx += 256)
        fr[idx/FE][idx%FE] = src[idx];
    __syncthreads();
    int j0 = threadIdx.x;
    float acc[7][2];
    #pragma unroll
    for (int n=0;n<7;n++){ acc[n][0]=0.f; acc[n][1]=0.f; }
    for (int k=0;k<FE;k++){
        float w0 = Wattn[(size_t)k*HI + j0];
        float w1 = Wattn[(size_t)k*HI + j0 + 256];
        #pragma unroll
        for (int n=0;n<7;n++){
            float fv = fr[n][k];
            acc[n][0] += fv*w0;
            acc[n][1] += fv*w1;
        }
    }
    int j1 = j0 + 256;
    #pragma unroll
    for (int n=0;n<7;n++){
        int p = b*NP + n0 + n;
        f_projB[((size_t)(j0>>5)*NPAIR + p)*32 + (j0&31)] = acc[n][0];
        f_projB[((size_t)(j1>>5)*NPAIR + p)*32 + (j1&31)] = acc[n][1];
    }
}

// fWcP[blk][b][n][c=32]: packed f[b,n,:] @ Wih[512:1024] for scan blocks
__global__ void k_fwc(const float* __restrict__ fT, const float* __restrict__ Wih,
                      float* __restrict__ fWcP){
    int b = blockIdx.z, ng = blockIdx.y, half = blockIdx.x;
    int n0 = ng*7;
    __shared__ float fr[7][FE];
    const float* src = fT + ((size_t)b*NP + n0)*FE;
    for (int idx = threadIdx.x; idx < 7*FE; idx += 256)
        fr[idx/FE][idx%FE] = src[idx];
    __syncthreads();
    int j0 = half*1024 + threadIdx.x;
    float acc[7][4];
    #pragma unroll
    for (int n=0;n<7;n++){ acc[n][0]=0.f; acc[n][1]=0.f; acc[n][2]=0.f; acc[n][3]=0.f; }
    const float* W = Wih + (size_t)512*G4;
    for (int k=0;k<FE;k++){
        float w0=W[(size_t)k*G4+j0], w1=W[(size_t)k*G4+j0+256], w2=W[(size_t)k*G4+j0+512], w3=W[(size_t)k*G4+j0+768];
        #pragma unroll
        for (int n=0;n<7;n++){
            float fv = fr[n][k];
            acc[n][0]+=fv*w0; acc[n][1]+=fv*w1; acc[n][2]+=fv*w2; acc[n][3]+=fv*w3;
        }
    }
    for (int n=0;n<7;n++){
        #pragma unroll
        for (int q=0;q<4;q++){
            int gc = j0 + q*256;
            int blk = (gc & 511) >> 3, m = gc & 7, g = gc >> 9;
            fWcP[(((size_t)blk*BB + b)*NP + n0+n)*32 + m*4+g] = acc[n][q];
        }
    }
}

// preGP[blk][t][b][c=32] = emb[captions[b,t]] @ Wih[0:512] + disWih[b], packed
__global__ void k_preg(const int* __restrict__ caps, const float* __restrict__ emb,
                       const float* __restrict__ Wih, const float* __restrict__ disWih,
                       float* __restrict__ preGP){
    int rg = blockIdx.y;      // 0..119 (row = b*60+t)
    int jt = blockIdx.x;      // 0..3
    int r0 = rg*16;
    __shared__ float er[16][EM];
    __shared__ int bidx[16];
    if (threadIdx.x < 16) bidx[threadIdx.x] = caps[r0 + threadIdx.x];
    __syncthreads();
    for (int idx = threadIdx.x; idx < 16*EM; idx += 256){
        int rl = idx >> 9, k = idx & 511;
        er[rl][k] = emb[(size_t)bidx[rl]*EM + k];
    }
    __syncthreads();
    int j = jt*512 + threadIdx.x;
    float acc[16][2];
    #pragma unroll
    for (int r=0;r<16;r++){ acc[r][0]=0.f; acc[r][1]=0.f; }
    for (int k=0;k<EM;k+=2){
        float w00 = Wih[(size_t)k*G4 + j],     w10 = Wih[(size_t)k*G4 + j + 256];
        float w01 = Wih[(size_t)(k+1)*G4 + j], w11 = Wih[(size_t)(k+1)*G4 + j + 256];
        #pragma unroll
        for (int r=0;r<16;r++){
            float2 e = *(const float2*)&er[r][k];
            acc[r][0] += e.x*w00 + e.y*w01;
            acc[r][1] += e.x*w10 + e.y*w11;
        }
    }
    for (int r=0;r<16;r++){
        int row = r0 + r;
        int b = row/60, t = row - b*60;
        #pragma unroll
        for (int q=0;q<2;q++){
            int gc = j + q*256;
            float v = acc[r][q] + disWih[b*G4 + gc];
            int blk = (gc & 511) >> 3, m = gc & 7, g = gc >> 9;
            preGP[(((size_t)blk*TT + t)*BB + b)*32 + m*4+g] = v;
        }
    }
}

// ---- store-arrive / checker-release grid barrier (R7 measured optimum) ----
__device__ __forceinline__ void gridbar(int* bar, int tgt){
    __syncthreads();
    if (threadIdx.x == 0){
        __threadfence();
        __hip_atomic_store(bar + blockIdx.x, tgt, __ATOMIC_RELAXED, __HIP_MEMORY_SCOPE_AGENT);
    }
    if (blockIdx.x == 0 && threadIdx.x < 64){
        int l = threadIdx.x;
        for (;;){
            int v0 = __hip_atomic_load(bar + l, __ATOMIC_RELAXED, __HIP_MEMORY_SCOPE_AGENT);
            int v1 = (l < NBLK-64) ? __hip_atomic_load(bar + 64 + l, __ATOMIC_RELAXED, __HIP_MEMORY_SCOPE_AGENT) : tgt;
            if (__all(v0 >= tgt && v1 >= tgt)) break;
            __builtin_amdgcn_s_sleep(1);
        }
        if (l == 0)
            __hip_atomic_store(bar + 128, tgt, __ATOMIC_RELAXED, __HIP_MEMORY_SCOPE_AGENT);
    }
    if (threadIdx.x == 0){
        while (__hip_atomic_load(bar + 128, __ATOMIC_RELAXED, __HIP_MEMORY_SCOPE_AGENT) < tgt)
            __builtin_amdgcn_s_sleep(1);
        __threadfence();
    }
    __syncthreads();
}

// cooperative scan, 2 barriers/step:
// phase A (all): MFMA h@Wslice -> LDS. a-blocks (64..79) then compute 32-col
// PARTIAL scores for all 1568 pairs from blocked f_projB (L2-resident,
// coalesced) -> scoresP[t][bkA][p]. barrier. gate blocks (0..63) sum 16
// partials, softmax, context, LSTM, publish h. barrier.
__launch_bounds__(512, 1)
__global__ void k_scan_coop(const float* __restrict__ f_projB, const float* __restrict__ fWcP,
                            const float* __restrict__ preGP, const float* __restrict__ daw,
                            const float* __restrict__ Wattn, const float* __restrict__ Whh,
                            const float* __restrict__ Wv,
                            float* __restrict__ h_seq, float* __restrict__ scoresP,
                            int* __restrict__ bar){
    __shared__ __align__(16) ushort h_hi[16384], h_lo[16384];   // 64 KiB
    __shared__ __align__(16) ushort w_hi[16384], w_lo[16384];   // 64 KiB
    __shared__ float al[32*52];
    __shared__ float gbuf[32*33];
    __shared__ float uni[NPAIR];    // a-blocks: daw slice (1024); gate: summed scores (1568)
    __shared__ float gv[32*36];
    __shared__ float cst[256];
    __shared__ float wvl[32];
    int bk = blockIdx.x;
    int tid = threadIdx.x;
    int lane = tid & 63, wave = tid >> 6;
    bool isGate = bk < 64;
    int bkA = bk - 64;

    // prologue: stage weights once as bf16 hi/lo, XOR-swizzled; daw, Wv, c-state
    {
        int k = tid;   // one W row per thread
        if (isGate){
            const float* wr = Whh + (size_t)k*G4 + bk*8;
            #pragma unroll
            for (int g = 0; g < 4; g++){
                float4 v0 = *(const float4*)(wr + g*512);
                float4 v1 = *(const float4*)(wr + g*512 + 4);
                float vv[8] = {v0.x,v0.y,v0.z,v0.w,v1.x,v1.y,v1.z,v1.w};
                #pragma unroll
                for (int u = 0; u < 8; u++){
                    int c = u*4 + g;
                    ushort hi = f2bf(vv[u]);
                    ushort lo = f2bf(vv[u] - bf2f(hi));
                    int idx = (c*512 + k) ^ ((c&7)<<3);
                    w_hi[idx] = hi; w_lo[idx] = lo;
                }
            }
        } else {
            const float* wr = Wattn + (size_t)(FE + k)*HI + bkA*32;
            #pragma unroll
            for (int cq = 0; cq < 8; cq++){
                float4 v = *(const float4*)(wr + cq*4);
                float vv[4] = {v.x,v.y,v.z,v.w};
                #pragma unroll
                for (int q = 0; q < 4; q++){
                    int c = cq*4 + q;
                    ushort hi = f2bf(vv[q]);
                    ushort lo = f2bf(vv[q] - bf2f(hi));
                    int idx = (c*512 + k) ^ ((c&7)<<3);
                    w_hi[idx] = hi; w_lo[idx] = lo;
                }
            }
            for (int i = tid; i < 1024; i += 512){
                int b = i >> 5, c = i & 31;
                uni[i] = daw[b*HI + bkA*32 + c];
            }
            if (tid < 32) wvl[tid] = Wv[bkA*32 + tid];
        }
        if (tid < 256) cst[tid] = 0.f;
    }
    __syncthreads();

    int tgt = 0;
    for (int t = 0; t < TT; t++){
        // stage h(t-1): fp32 h_seq -> bf16 hi/lo LDS, coalesced reads, swizzled writes
        if (t == 0){
            uint4 z = make_uint4(0,0,0,0);
            #pragma unroll
            for (int it = 0; it < 4; it++){
                int flat = (it*512 + tid)*8;
                int b = flat >> 9, k = flat & 511;
                int di = (b*512 + k) ^ ((b&7)<<3);
                *(uint4*)&h_hi[di] = z;
                *(uint4*)&h_lo[di] = z;
            }
        } else {
            const float* hs = h_seq + (size_t)(t-1)*BB*HI;
            #pragma unroll
            for (int it = 0; it < 4; it++){
                int flat = (it*512 + tid)*8;
                int b = flat >> 9, k = flat & 511;
                float4 v0 = *(const float4*)(hs + flat);
                float4 v1 = *(const float4*)(hs + flat + 4);
                float fv[8] = {v0.x,v0.y,v0.z,v0.w,v1.x,v1.y,v1.z,v1.w};
                union { ushort u[8]; uint4 v; } ph, pl;
                #pragma unroll
                for (int j = 0; j < 8; j++){
                    ushort hi = f2bf(fv[j]);
                    ph.u[j] = hi;
                    pl.u[j] = f2bf(fv[j] - bf2f(hi));
                }
                int di = (b*512 + k) ^ ((b&7)<<3);
                *(uint4*)&h_hi[di] = ph.v;
                *(uint4*)&h_lo[di] = pl.v;
            }
        }
        __syncthreads();

        // phase A: 32x32 = h(32x512) @ Wslice(512x32) via MFMA, hi/lo split -> gbuf
        if (wave < 4){
            int rbase = (wave >> 1) * 16, cbase = (wave & 1) * 16;
            int m = lane & 15, kg = lane >> 4;
            int arow = rbase + m, bcol = cbase + m;
            int abase = arow*512 + kg*8, axr = (arow&7)<<3;
            int bbase = bcol*512 + kg*8, bxr = (bcol&7)<<3;
            float4v acc = {0.f,0.f,0.f,0.f};
            #pragma unroll
            for (int ks = 0; ks < 16; ks++){
                int ai = (abase + ks*32) ^ axr;
                int bi = (bbase + ks*32) ^ bxr;
                short8v ahi = *(const short8v*)&h_hi[ai];
                short8v alo = *(const short8v*)&h_lo[ai];
                short8v bhi = *(const short8v*)&w_hi[bi];
                short8v blo = *(const short8v*)&w_lo[bi];
                acc = __builtin_amdgcn_mfma_f32_16x16x32_bf16(ahi, bhi, acc, 0,0,0);
                acc = __builtin_amdgcn_mfma_f32_16x16x32_bf16(alo, bhi, acc, 0,0,0);
                acc = __builtin_amdgcn_mfma_f32_16x16x32_bf16(ahi, blo, acc, 0,0,0);
            }
            int ccol = cbase + (lane & 15);
            int crow0 = rbase + (lane >> 4)*4;
            if (isGate){
                #pragma unroll
                for (int r = 0; r < 4; r++)
                    gbuf[(crow0+r)*33 + ccol] = acc[r];
            } else {
                #pragma unroll
                for (int r = 0; r < 4; r++)
                    gbuf[(crow0+r)*33 + ccol] = acc[r] + uni[(crow0+r)*32 + ccol];
            }
        }
        __syncthreads();

        float g0r = 0.f, g1r = 0.f;
        if (!isGate){
            // phase B (a-blocks): partial scores over own 32 cols, lane-per-pair
            const float* fB = f_projB + (size_t)bkA*NPAIR*32;
            float* spt = scoresP + ((size_t)t*16 + bkA)*NPAIR;
            #pragma unroll
            for (int it = 0; it < 4; it++){
                int p = it*512 + tid;
                if (p < NPAIR){
                    int pb = (int)((unsigned)p/49u);
                    const float* ga = &gbuf[pb*33];
                    const float4* f4 = (const float4*)(fB + (size_t)p*32);
                    float s = 0.f;
                    #pragma unroll
                    for (int c4 = 0; c4 < 8; c4++){
                        float4 fv = f4[c4];
                        int c = c4*4;
                        s += wvl[c+0]*ftanh(fv.x + ga[c+0])
                           + wvl[c+1]*ftanh(fv.y + ga[c+1])
                           + wvl[c+2]*ftanh(fv.z + ga[c+2])
                           + wvl[c+3]*ftanh(fv.w + ga[c+3]);
                    }
                    spt[p] = s;
                }
            }
        } else {
            // gate blocks: prefetch gate partial (gbuf + preGP) into registers
            int b = tid >> 4, cp = tid & 15;
            const float* pgp = preGP + (((size_t)bk*TT + t)*BB + b)*32;
            g0r = gbuf[b*33 + cp] + pgp[cp];
            g1r = gbuf[b*33 + cp + 16] + pgp[cp + 16];
        }
        gridbar(bar, ++tgt);

        // phase C (gate blocks): sum partials, softmax, context, LSTM
        if (isGate){
            const float* spt = scoresP + (size_t)t*16*NPAIR;
            #pragma unroll
            for (int it = 0; it < 4; it++){
                int p = it*512 + tid;
                if (p < NPAIR){
                    float s = 0.f;
                    #pragma unroll
                    for (int k2 = 0; k2 < 16; k2++) s += spt[(size_t)k2*NPAIR + p];
                    uni[p] = s;
                }
            }
            __syncthreads();
            {
                int hw = tid >> 5, l32 = tid & 31;
                #pragma unroll
                for (int rep = 0; rep < 2; rep++){
                    int b = hw + rep*16;
                    const float* sb = uni + b*NP;
                    float s0 = sb[l32];
                    float s1 = (l32 < 17) ? sb[32 + l32] : -1e30f;
                    float m = fmaxf(s0, s1);
                    #pragma unroll
                    for (int off = 16; off; off >>= 1) m = fmaxf(m, __shfl_xor(m, off, 32));
                    float e0 = __expf(s0 - m);
                    float e1 = (l32 < 17) ? __expf(s1 - m) : 0.f;
                    float sm = e0 + e1;
                    #pragma unroll
                    for (int off = 16; off; off >>= 1) sm += __shfl_xor(sm, off, 32);
                    float inv = 1.f / sm;
                    al[b*52 + l32] = e0*inv;
                    if (l32 < 17) al[b*52 + 32 + l32] = e1*inv;
                }
            }
            __syncthreads();
            {
                int b = tid >> 4, cp = tid & 15;
                const float* fw = fWcP + (((size_t)bk*BB + b)*NP)*32;
                for (int n = 0; n < NP; n++){
                    float av = al[b*52 + n];
                    g0r += av*fw[n*32 + cp];
                    g1r += av*fw[n*32 + cp + 16];
                }
                gv[b*36 + cp]      = g0r;
                gv[b*36 + cp + 16] = g1r;
            }
            __syncthreads();
            if (tid < 256){
                int b = tid >> 3, m = tid & 7;
                float gi = gv[b*36 + m*4 + 0];
                float gf = gv[b*36 + m*4 + 1];
                float gg = gv[b*36 + m*4 + 2];
                float go = gv[b*36 + m*4 + 3];
                float cn = fsig(gf)*cst[b*8 + m] + fsig(gi)*ftanh(gg);
                float hn = fsig(go)*ftanh(cn);
                cst[b*8 + m] = cn;
                h_seq[(size_t)t*BB*HI + b*HI + bk*8 + m] = hn;
            }
        }
        gridbar(bar, ++tgt);
    }
}

// out[b,t,v] = h_seq[t,b,:] @ W_fc + b_fc  — MFMA (hi/lo bf16 split), one t per block
__launch_bounds__(512, 1)
__global__ void k_logits(const float* __restrict__ h_seq, const float* __restrict__ Wfc,
                         const float* __restrict__ bfc, float* __restrict__ out){
    __shared__ __align__(16) ushort h_hi[16384], h_lo[16384];
    int t = blockIdx.x, vt = blockIdx.y;
    int tid = threadIdx.x, lane = tid & 63, wave = tid >> 6;
    const float* hs = h_seq + (size_t)t*BB*HI;
    #pragma unroll
    for (int it = 0; it < 4; it++){
        int flat = (it*512 + tid)*8;
        int b = flat >> 9, k = flat & 511;
        float4 v0 = *(const float4*)(hs + flat);
        float4 v1 = *(const float4*)(hs + flat + 4);
        float fv[8] = {v0.x,v0.y,v0.z,v0.w,v1.x,v1.y,v1.z,v1.w};
        union { ushort u[8]; uint4 v; } ph, pl;
        #pragma unroll
        for (int j = 0; j < 8; j++){
            ushort hi = f2bf(fv[j]);
            ph.u[j] = hi;
            pl.u[j] = f2bf(fv[j] - bf2f(hi));
        }
        int di = (b*512 + k) ^ ((b&7)<<3);
        *(uint4*)&h_hi[di] = ph.v;
        *(uint4*)&h_lo[di] = pl.v;
    }
    __syncthreads();

    int m = lane & 15, kg = lane >> 4;
    int cb = vt*256 + wave*32;
    int a0 = m*512 + kg*8;
    int a1 = (16+m)*512 + kg*8;
    int axr = (m&7)<<3;
    float4v acc[2][2];
    acc[0][0]=(float4v){0,0,0,0}; acc[0][1]=(float4v){0,0,0,0};
    acc[1][0]=(float4v){0,0,0,0}; acc[1][1]=(float4v){0,0,0,0};
    const short8v bz = {0,0,0,0,0,0,0,0};

    for (int ks = 0; ks < 16; ks++){
        short8v ah0 = *(const short8v*)&h_hi[(a0 + ks*32) ^ axr];
        short8v al0 = *(const short8v*)&h_lo[(a0 + ks*32) ^ axr];
        short8v ah1 = *(const short8v*)&h_hi[(a1 + ks*32) ^ axr];
        short8v al1 = *(const short8v*)&h_lo[(a1 + ks*32) ^ axr];
        #pragma unroll
        for (int cj = 0; cj < 2; cj++){
            int v = cb + cj*16 + m;
            short8v bhi = bz, blo = bz;
            if (v < NV){
                int k0 = ks*32 + kg*8;
                const float* wp = Wfc + (size_t)k0*NV + v;
                float w[8];
                #pragma unroll
                for (int i = 0; i < 8; i++) w[i] = wp[(size_t)i*NV];
                union { ushort u[8]; short8v s; } bh, bl;
                #pragma unroll
                for (int i = 0; i < 8; i++){
                    ushort hi = f2bf(w[i]);
                    bh.u[i] = hi;
                    bl.u[i] = f2bf_trunc(w[i] - bf2f(hi));
                }
                bhi = bh.s; blo = bl.s;
            }
            acc[0][cj] = __builtin_amdgcn_mfma_f32_16x16x32_bf16(ah0, bhi, acc[0][cj], 0,0,0);
            acc[0][cj] = __builtin_amdgcn_mfma_f32_16x16x32_bf16(al0, bhi, acc[0][cj], 0,0,0);
            acc[0][cj] = __builtin_amdgcn_mfma_f32_16x16x32_bf16(ah0, blo, acc[0][cj], 0,0,0);
            acc[1][cj] = __builtin_amdgcn_mfma_f32_16x16x32_bf16(ah1, bhi, acc[1][cj], 0,0,0);
            acc[1][cj] = __builtin_amdgcn_mfma_f32_16x16x32_bf16(al1, bhi, acc[1][cj], 0,0,0);
            acc[1][cj] = __builtin_amdgcn_mfma_f32_16x16x32_bf16(ah1, blo, acc[1][cj], 0,0,0);
        }
    }
    #pragma unroll
    for (int cj = 0; cj < 2; cj++){
        int v = cb + cj*16 + m;
        if (v < NV){
            float bias = bfc[v];
            #pragma unroll
            for (int ri = 0; ri < 2; ri++){
                int b0 = ri*16 + kg*4;
                #pragma unroll
                for (int r = 0; r < 4; r++)
                    out[((size_t)(b0+r)*TT + t)*NV + v] = acc[ri][cj][r] + bias;
            }
        }
    }
}

extern "C" void kernel_launch(void* const* d_in, const int* in_sizes, int n_in,
                              void* d_out, int out_size, void* d_ws, size_t ws_size,
                              hipStream_t stream){
    const float* features = (const float*)d_in[0];
    const int*   captions = (const int*)d_in[1];
    const float* disease  = (const float*)d_in[2];
    const float* emb      = (const float*)d_in[3];
    const float* W_attn   = (const float*)d_in[4];
    const float* b_attn   = (const float*)d_in[5];
    const float* W_v      = (const float*)d_in[6];
    // d_in[7] = b_v : constant shift, cancels in softmax
    const float* W_dp1    = (const float*)d_in[8];
    const float* b_dp1    = (const float*)d_in[9];
    const float* W_dp2    = (const float*)d_in[10];
    const float* b_dp2    = (const float*)d_in[11];
    const float* W_de1    = (const float*)d_in[12];
    const float* b_de1    = (const float*)d_in[13];
    const float* W_de2    = (const float*)d_in[14];
    const float* b_de2    = (const float*)d_in[15];
    const float* W_ih     = (const float*)d_in[16];
    const float* W_hh     = (const float*)d_in[17];
    const float* b_ih     = (const float*)d_in[18];
    const float* b_hh     = (const float*)d_in[19];
    const float* W_fc     = (const float*)d_in[20];
    const float* b_fc     = (const float*)d_in[21];
    float* out = (float*)d_out;

    // ws: h_seq (read by k_logits while it writes d_out) + barrier state
    const size_t N_HSEQ = (size_t)TT*BB*HI;          // 983040
    float* h_seq = (float*)d_ws;
    int*   bar   = (int*)((char*)d_ws + N_HSEQ*sizeof(float));

    // all other scratch lives in d_out (never read by k_logits; k_logits
    // fully overwrites d_out last)
    const size_t N_FT   = (size_t)BB*NP*FE;          // 802816
    const size_t N_FPB  = (size_t)16*NPAIR*32;       // 802816 (f_projB)
    const size_t N_FWC  = (size_t)BB*NP*G4;          // 3211264
    const size_t N_PREG = (size_t)BB*TT*G4;          // 3932160
    const size_t N_SCP  = (size_t)TT*16*NPAIR;       // 1505280
    float* fT     = out;
    float* f_projB= fT + N_FT;
    float* fWcP   = f_projB + N_FPB;
    float* preGP  = fWcP + N_FWC;
    float* scoresP= preGP + N_PREG;
    float* disWih = scoresP + N_SCP;
    float* daw    = disWih + (size_t)BB*G4;

    hipMemsetAsync(bar, 0, 1024, stream);
    k_transpose<<<dim3(8,BB),256,0,stream>>>(features, fT);
    k_disease<<<BB,256,0,stream>>>(disease, W_dp1,b_dp1,W_dp2,b_dp2,
                                   W_de1,b_de1,W_de2,b_de2,
                                   W_attn,b_attn, W_ih,b_ih,b_hh,
                                   daw, disWih);
    k_fproj<<<dim3(7,BB),256,0,stream>>>(fT, W_attn, f_projB);
    k_fwc<<<dim3(2,7,BB),256,0,stream>>>(fT, W_ih, fWcP);
    k_preg<<<dim3(4,120),256,0,stream>>>(captions, emb, W_ih, disWih, preGP);
    k_scan_coop<<<NBLK,512,0,stream>>>(f_projB, fWcP, preGP, daw,
                                       W_attn, W_hh, W_v,
                                       h_seq, scoresP, bar);
    k_logits<<<dim3(TT,40),512,0,stream>>>(h_seq, W_fc, b_fc, out);
}

// Round 12
// 1835.088 us; speedup vs baseline: 1.3483x; 1.3483x over previous
//
#include <hip/hip_runtime.h>
#include <math.h>

#define BB 32      // batch
#define NP 49      // spatial positions 7*7
#define FE 512     // FEAT
#define HI 512     // HID
#define EM 512     // emb dim
#define TT 60      // timesteps
#define G4 2048    // 4*HID
#define NV 10000   // vocab
#define ND 14      // disease dim
#define NBLK 80    // cooperative scan blocks: 64 gate + 16 a

typedef __attribute__((ext_vector_type(8))) short short8v;
typedef __attribute__((ext_vector_type(4))) float float4v;

__device__ __forceinline__ float fsig(float x){ return 1.0f/(1.0f+__expf(-x)); }
__device__ __forceinline__ float ftanh(float x){
    x = fminf(fmaxf(x, -15.0f), 15.0f);
    float e = __expf(2.0f*x);
    return (e-1.0f)/(e+1.0f);
}
__device__ __forceinline__ ushort f2bf(float x){
    union { float f; unsigned u; } v; v.f = x;
    unsigned r = v.u + 0x7fff + ((v.u >> 16) & 1);
    return (ushort)(r >> 16);
}
__device__ __forceinline__ float bf2f(ushort h){
    union { float f; unsigned u; } v; v.u = ((unsigned)h) << 16;
    return v.f;
}
__device__ __forceinline__ ushort f2bf_trunc(float x){
    return (ushort)(__float_as_uint(x) >> 16);
}

// features (B,512,49) -> fT (B,49,512)
__global__ void k_transpose(const float* __restrict__ feat, float* __restrict__ fT){
    int b = blockIdx.y;
    int cb = blockIdx.x * 64;
    __shared__ float tile[64][NP+1];
    const float* src = feat + (size_t)b*FE*NP;
    for (int idx = threadIdx.x; idx < 64*NP; idx += 256){
        int cl = idx / NP, n = idx % NP;
        tile[cl][n] = src[(size_t)(cb+cl)*NP + n];
    }
    __syncthreads();
    float* dst = fT + (size_t)b*NP*FE;
    for (int idx = threadIdx.x; idx < 64*NP; idx += 256){
        int cl = idx % 64, n = idx / 64;
        dst[(size_t)n*FE + cb + cl] = tile[cl][n];
    }
}

// per-batch disease MLPs + folded projections
__global__ void k_disease(const float* __restrict__ dis,
                          const float* __restrict__ Wdp1, const float* __restrict__ bdp1,
                          const float* __restrict__ Wdp2, const float* __restrict__ bdp2,
                          const float* __restrict__ Wde1, const float* __restrict__ bde1,
                          const float* __restrict__ Wde2, const float* __restrict__ bde2,
                          const float* __restrict__ Wattn, const float* __restrict__ battn,
                          const float* __restrict__ Wih, const float* __restrict__ bih,
                          const float* __restrict__ bhh,
                          float* __restrict__ daw, float* __restrict__ disWih){
    int b = blockIdx.x;
    int tid = threadIdx.x;
    __shared__ float d[ND];
    __shared__ float hp[128], he[128];
    __shared__ float datt[HI];
    __shared__ float dctx[256];
    if (tid < ND) d[tid] = dis[b*ND + tid];
    __syncthreads();
    if (tid < 128){
        float accP = bdp1[tid], accE = bde1[tid];
        for (int k=0;k<ND;k++){ accP += d[k]*Wdp1[k*128+tid]; accE += d[k]*Wde1[k*128+tid]; }
        hp[tid] = fmaxf(accP, 0.f);
        he[tid] = fmaxf(accE, 0.f);
    }
    __syncthreads();
    for (int j = tid; j < HI; j += 256){
        float a = bdp2[j];
        for (int k=0;k<128;k++) a += hp[k]*Wdp2[k*HI+j];
        datt[j] = a;
    }
    if (tid < 256){
        float a = bde2[tid];
        for (int k=0;k<128;k++) a += he[k]*Wde2[k*256+tid];
        dctx[tid] = a;
    }
    __syncthreads();
    for (int j = tid; j < HI; j += 256){
        float a = battn[j];
        for (int k=0;k<HI;k++) a += datt[k]*Wattn[(size_t)(FE+k)*HI + j];
        daw[b*HI + j] = a;
    }
    for (int j = tid; j < G4; j += 256){
        float a = bih[j] + bhh[j];
        for (int k=0;k<256;k++) a += dctx[k]*Wih[(size_t)(EM+FE+k)*G4 + j];
        disWih[b*G4 + j] = a;
    }
}

// f_proj[b,n,:] = f[b,n,:] @ W_attn[:512]
__global__ void k_fproj(const float* __restrict__ fT, const float* __restrict__ Wattn,
                        float* __restrict__ f_proj){
    int b = blockIdx.y, ng = blockIdx.x;
    int n0 = ng*7;
    __shared__ float fr[7][FE];
    const float* src = fT + ((size_t)b*NP + n0)*FE;
    for (int idx = threadIdx.x; idx < 7*FE; idx += 256)
        fr[idx/FE][idx%FE] = src[idx];
    __syncthreads();
    int j0 = threadIdx.x;
    float acc[7][2];
    #pragma unroll
    for (int n=0;n<7;n++){ acc[n][0]=0.f; acc[n][1]=0.f; }
    for (int k=0;k<FE;k++){
        float w0 = Wattn[(size_t)k*HI + j0];
        float w1 = Wattn[(size_t)k*HI + j0 + 256];
        #pragma unroll
        for (int n=0;n<7;n++){
            float fv = fr[n][k];
            acc[n][0] += fv*w0;
            acc[n][1] += fv*w1;
        }
    }
    float* dst = f_proj + ((size_t)b*NP + n0)*HI;
    #pragma unroll
    for (int n=0;n<7;n++){
        dst[(size_t)n*HI + j0] = acc[n][0];
        dst[(size_t)n*HI + j0+256] = acc[n][1];
    }
}

// fWcP[blk][b][n][c=32]: packed f[b,n,:] @ Wih[512:1024] for scan blocks
__global__ void k_fwc(const float* __restrict__ fT, const float* __restrict__ Wih,
                      float* __restrict__ fWcP){
    int b = blockIdx.z, ng = blockIdx.y, half = blockIdx.x;
    int n0 = ng*7;
    __shared__ float fr[7][FE];
    const float* src = fT + ((size_t)b*NP + n0)*FE;
    for (int idx = threadIdx.x; idx < 7*FE; idx += 256)
        fr[idx/FE][idx%FE] = src[idx];
    __syncthreads();
    int j0 = half*1024 + threadIdx.x;
    float acc[7][4];
    #pragma unroll
    for (int n=0;n<7;n++){ acc[n][0]=0.f; acc[n][1]=0.f; acc[n][2]=0.f; acc[n][3]=0.f; }
    const float* W = Wih + (size_t)512*G4;
    for (int k=0;k<FE;k++){
        float w0=W[(size_t)k*G4+j0], w1=W[(size_t)k*G4+j0+256], w2=W[(size_t)k*G4+j0+512], w3=W[(size_t)k*G4+j0+768];
        #pragma unroll
        for (int n=0;n<7;n++){
            float fv = fr[n][k];
            acc[n][0]+=fv*w0; acc[n][1]+=fv*w1; acc[n][2]+=fv*w2; acc[n][3]+=fv*w3;
        }
    }
    for (int n=0;n<7;n++){
        #pragma unroll
        for (int q=0;q<4;q++){
            int gc = j0 + q*256;
            int blk = (gc & 511) >> 3, m = gc & 7, g = gc >> 9;
            fWcP[(((size_t)blk*BB + b)*NP + n0+n)*32 + m*4+g] = acc[n][q];
        }
    }
}

// preGP[blk][t][b][c=32] = emb[captions[b,t]] @ Wih[0:512] + disWih[b], packed
__global__ void k_preg(const int* __restrict__ caps, const float* __restrict__ emb,
                       const float* __restrict__ Wih, const float* __restrict__ disWih,
                       float* __restrict__ preGP){
    int rg = blockIdx.y;      // 0..119 (row = b*60+t)
    int jt = blockIdx.x;      // 0..3
    int r0 = rg*16;
    __shared__ float er[16][EM];
    __shared__ int bidx[16];
    if (threadIdx.x < 16) bidx[threadIdx.x] = caps[r0 + threadIdx.x];
    __syncthreads();
    for (int idx = threadIdx.x; idx < 16*EM; idx += 256){
        int rl = idx >> 9, k = idx & 511;
        er[rl][k] = emb[(size_t)bidx[rl]*EM + k];
    }
    __syncthreads();
    int j = jt*512 + threadIdx.x;
    float acc[16][2];
    #pragma unroll
    for (int r=0;r<16;r++){ acc[r][0]=0.f; acc[r][1]=0.f; }
    for (int k=0;k<EM;k+=2){
        float w00 = Wih[(size_t)k*G4 + j],     w10 = Wih[(size_t)k*G4 + j + 256];
        float w01 = Wih[(size_t)(k+1)*G4 + j], w11 = Wih[(size_t)(k+1)*G4 + j + 256];
        #pragma unroll
        for (int r=0;r<16;r++){
            float2 e = *(const float2*)&er[r][k];
            acc[r][0] += e.x*w00 + e.y*w01;
            acc[r][1] += e.x*w10 + e.y*w11;
        }
    }
    for (int r=0;r<16;r++){
        int row = r0 + r;
        int b = row/60, t = row - b*60;
        #pragma unroll
        for (int q=0;q<2;q++){
            int gc = j + q*256;
            float v = acc[r][q] + disWih[b*G4 + gc];
            int blk = (gc & 511) >> 3, m = gc & 7, g = gc >> 9;
            preGP[(((size_t)blk*TT + t)*BB + b)*32 + m*4+g] = v;
        }
    }
}

// ---- store-arrive / checker-release grid barrier, release/relaxed form ----
// Producer arrival uses a RELEASE atomic store (vmcnt drain + L2 writeback,
// NO invalidate). Spinners poll RELAXED with no acquire fence: every
// cross-block datum is written to a fresh t-indexed, line-aligned address
// that no consumer cache has ever held, and all other arrays are read-only
// during the scan — so invalidates are unnecessary and L2 stays warm.
__device__ __forceinline__ void gridbar(int* bar, int tgt){
    __syncthreads();
    if (threadIdx.x == 0)
        __hip_atomic_store(bar + blockIdx.x, tgt, __ATOMIC_RELEASE, __HIP_MEMORY_SCOPE_AGENT);
    if (blockIdx.x == 0 && threadIdx.x < 64){
        int l = threadIdx.x;
        for (;;){
            int v0 = __hip_atomic_load(bar + l, __ATOMIC_RELAXED, __HIP_MEMORY_SCOPE_AGENT);
            int v1 = (l < NBLK-64) ? __hip_atomic_load(bar + 64 + l, __ATOMIC_RELAXED, __HIP_MEMORY_SCOPE_AGENT) : tgt;
            if (__all(v0 >= tgt && v1 >= tgt)) break;
            __builtin_amdgcn_s_sleep(1);
        }
        if (l == 0)
            __hip_atomic_store(bar + 128, tgt, __ATOMIC_RELEASE, __HIP_MEMORY_SCOPE_AGENT);
    }
    if (threadIdx.x == 0){
        while (__hip_atomic_load(bar + 128, __ATOMIC_RELAXED, __HIP_MEMORY_SCOPE_AGENT) < tgt)
            __builtin_amdgcn_s_sleep(1);
    }
    __syncthreads();
}

// cooperative scan (R10 structure; MFMA phase A; 3 barriers/step):
// blocks 0..63 gate (8 packed hid cols x 4 gates), blocks 64..79 a-slices
__launch_bounds__(512, 1)
__global__ void k_scan_coop(const float* __restrict__ f_proj, const float* __restrict__ fWcP,
                            const float* __restrict__ preGP, const float* __restrict__ daw,
                            const float* __restrict__ Wattn, const float* __restrict__ Whh,
                            const float* __restrict__ Wv,
                            float* __restrict__ h_seq, float* __restrict__ a_buf,
                            float* __restrict__ scores, int* __restrict__ bar){
    __shared__ __align__(16) ushort h_hi[16384], h_lo[16384];   // 64 KiB
    __shared__ __align__(16) ushort w_hi[16384], w_lo[16384];   // 64 KiB
    __shared__ float al[32*52];
    __shared__ float gbuf[32*33];
    __shared__ float daw_lds[32*32];
    __shared__ float gv[32*36];
    __shared__ float cst[256];
    __shared__ float wvl[512];
    int bk = blockIdx.x;
    int tid = threadIdx.x;
    int lane = tid & 63, wave = tid >> 6;
    bool isGate = bk < 64;

    // prologue: stage weights once as bf16 hi/lo, XOR-swizzled; daw, Wv, c-state
    {
        int k = tid;   // one W row per thread
        if (isGate){
            const float* wr = Whh + (size_t)k*G4 + bk*8;
            #pragma unroll
            for (int g = 0; g < 4; g++){
                float4 v0 = *(const float4*)(wr + g*512);
                float4 v1 = *(const float4*)(wr + g*512 + 4);
                float vv[8] = {v0.x,v0.y,v0.z,v0.w,v1.x,v1.y,v1.z,v1.w};
                #pragma unroll
                for (int u = 0; u < 8; u++){
                    int c = u*4 + g;
                    ushort hi = f2bf(vv[u]);
                    ushort lo = f2bf(vv[u] - bf2f(hi));
                    int idx = (c*512 + k) ^ ((c&7)<<3);
                    w_hi[idx] = hi; w_lo[idx] = lo;
                }
            }
        } else {
            const float* wr = Wattn + (size_t)(FE + k)*HI + (bk-64)*32;
            #pragma unroll
            for (int cq = 0; cq < 8; cq++){
                float4 v = *(const float4*)(wr + cq*4);
                float vv[4] = {v.x,v.y,v.z,v.w};
                #pragma unroll
                for (int q = 0; q < 4; q++){
                    int c = cq*4 + q;
                    ushort hi = f2bf(vv[q]);
                    ushort lo = f2bf(vv[q] - bf2f(hi));
                    int idx = (c*512 + k) ^ ((c&7)<<3);
                    w_hi[idx] = hi; w_lo[idx] = lo;
                }
            }
            for (int i = tid; i < 1024; i += 512){
                int b = i >> 5, c = i & 31;
                daw_lds[i] = daw[b*HI + (bk-64)*32 + c];
            }
        }
        if (tid < 256) cst[tid] = 0.f;
        wvl[tid] = Wv[tid];
    }
    __syncthreads();

    int tgt = 0;
    for (int t = 0; t < TT; t++){
        // stage h(t-1): fp32 h_seq -> bf16 hi/lo LDS, coalesced reads, swizzled writes
        if (t == 0){
            uint4 z = make_uint4(0,0,0,0);
            #pragma unroll
            for (int it = 0; it < 4; it++){
                int flat = (it*512 + tid)*8;
                int b = flat >> 9, k = flat & 511;
                int di = (b*512 + k) ^ ((b&7)<<3);
                *(uint4*)&h_hi[di] = z;
                *(uint4*)&h_lo[di] = z;
            }
        } else {
            const float* hs = h_seq + (size_t)(t-1)*BB*HI;
            #pragma unroll
            for (int it = 0; it < 4; it++){
                int flat = (it*512 + tid)*8;
                int b = flat >> 9, k = flat & 511;
                float4 v0 = *(const float4*)(hs + flat);
                float4 v1 = *(const float4*)(hs + flat + 4);
                float fv[8] = {v0.x,v0.y,v0.z,v0.w,v1.x,v1.y,v1.z,v1.w};
                union { ushort u[8]; uint4 v; } ph, pl;
                #pragma unroll
                for (int j = 0; j < 8; j++){
                    ushort hi = f2bf(fv[j]);
                    ph.u[j] = hi;
                    pl.u[j] = f2bf(fv[j] - bf2f(hi));
                }
                int di = (b*512 + k) ^ ((b&7)<<3);
                *(uint4*)&h_hi[di] = ph.v;
                *(uint4*)&h_lo[di] = pl.v;
            }
        }
        __syncthreads();

        // phase A: 32x32 = h(32x512) @ Wslice(512x32) via MFMA, hi/lo split
        if (wave < 4){
            int rbase = (wave >> 1) * 16, cbase = (wave & 1) * 16;
            int m = lane & 15, kg = lane >> 4;
            int arow = rbase + m, bcol = cbase + m;
            int abase = arow*512 + kg*8, axr = (arow&7)<<3;
            int bbase = bcol*512 + kg*8, bxr = (bcol&7)<<3;
            float4v acc = {0.f,0.f,0.f,0.f};
            #pragma unroll
            for (int ks = 0; ks < 16; ks++){
                int ai = (abase + ks*32) ^ axr;
                int bi = (bbase + ks*32) ^ bxr;
                short8v ahi = *(const short8v*)&h_hi[ai];
                short8v alo = *(const short8v*)&h_lo[ai];
                short8v bhi = *(const short8v*)&w_hi[bi];
                short8v blo = *(const short8v*)&w_lo[bi];
                acc = __builtin_amdgcn_mfma_f32_16x16x32_bf16(ahi, bhi, acc, 0,0,0);
                acc = __builtin_amdgcn_mfma_f32_16x16x32_bf16(alo, bhi, acc, 0,0,0);
                acc = __builtin_amdgcn_mfma_f32_16x16x32_bf16(ahi, blo, acc, 0,0,0);
            }
            int ccol = cbase + (lane & 15);
            int crow0 = rbase + (lane >> 4)*4;
            if (isGate){
                #pragma unroll
                for (int r = 0; r < 4; r++)
                    gbuf[(crow0+r)*33 + ccol] = acc[r];
            } else {
                int cb = (bk-64)*32;
                float* ab = a_buf + (size_t)t*BB*HI;
                #pragma unroll
                for (int r = 0; r < 4; r++)
                    ab[(size_t)(crow0+r)*HI + cb + ccol] = acc[r] + daw_lds[(crow0+r)*32 + ccol];
            }
        }
        gridbar(bar, ++tgt);

        // phase B: scores[b,n] = Wv . tanh(f_proj[b,n,:] + a[b,:])  (all blocks)
        {
            int wid = tid >> 6, l = tid & 63;
            for (int p = bk + wid*NBLK; p < BB*NP; p += NBLK*8){
                int pb = p / NP, pn = p - pb*NP;
                const float* fpn = f_proj + ((size_t)pb*NP + pn)*HI;
                const float* at  = a_buf + ((size_t)t*BB + pb)*HI;
                int j = l*8;
                float4 f0 = *(const float4*)(fpn + j);
                float4 a0 = *(const float4*)(at + j);
                float4 f1 = *(const float4*)(fpn + j + 4);
                float4 a1 = *(const float4*)(at + j + 4);
                float s = wvl[j+0]*ftanh(f0.x + a0.x)
                        + wvl[j+1]*ftanh(f0.y + a0.y)
                        + wvl[j+2]*ftanh(f0.z + a0.z)
                        + wvl[j+3]*ftanh(f0.w + a0.w)
                        + wvl[j+4]*ftanh(f1.x + a1.x)
                        + wvl[j+5]*ftanh(f1.y + a1.y)
                        + wvl[j+6]*ftanh(f1.z + a1.z)
                        + wvl[j+7]*ftanh(f1.w + a1.w);
                #pragma unroll
                for (int off = 32; off; off >>= 1) s += __shfl_xor(s, off);
                if (l == 0) scores[t*(BB*NP) + p] = s;
            }
        }
        gridbar(bar, ++tgt);

        // phase C: softmax + gates + LSTM (gate blocks only)
        if (isGate){
            int hw = tid >> 5, l32 = tid & 31;
            #pragma unroll
            for (int rep = 0; rep < 2; rep++){
                int b = hw + rep*16;
                const float* sb = scores + t*(BB*NP) + b*NP;
                float s0 = sb[l32];
                float s1 = (l32 < 17) ? sb[32 + l32] : -1e30f;
                float m = fmaxf(s0, s1);
                #pragma unroll
                for (int off = 16; off; off >>= 1) m = fmaxf(m, __shfl_xor(m, off, 32));
                float e0 = __expf(s0 - m);
                float e1 = (l32 < 17) ? __expf(s1 - m) : 0.f;
                float sm = e0 + e1;
                #pragma unroll
                for (int off = 16; off; off >>= 1) sm += __shfl_xor(sm, off, 32);
                float inv = 1.f / sm;
                al[b*52 + l32] = e0*inv;
                if (l32 < 17) al[b*52 + 32 + l32] = e1*inv;
            }
            __syncthreads();
            {
                int b = tid >> 4, cp = tid & 15;
                float g0 = gbuf[b*33 + cp];
                float g1 = gbuf[b*33 + cp + 16];
                const float* pgp = preGP + (((size_t)bk*TT + t)*BB + b)*32;
                g0 += pgp[cp];
                g1 += pgp[cp + 16];
                const float* fw = fWcP + (((size_t)bk*BB + b)*NP)*32;
                for (int n = 0; n < NP; n++){
                    float av = al[b*52 + n];
                    g0 += av*fw[n*32 + cp];
                    g1 += av*fw[n*32 + cp + 16];
                }
                gv[b*36 + cp]      = g0;
                gv[b*36 + cp + 16] = g1;
            }
            __syncthreads();
            if (tid < 256){
                int b = tid >> 3, m = tid & 7;
                float gi = gv[b*36 + m*4 + 0];
                float gf = gv[b*36 + m*4 + 1];
                float gg = gv[b*36 + m*4 + 2];
                float go = gv[b*36 + m*4 + 3];
                float cn = fsig(gf)*cst[b*8 + m] + fsig(gi)*ftanh(gg);
                float hn = fsig(go)*ftanh(cn);
                cst[b*8 + m] = cn;
                h_seq[(size_t)t*BB*HI + b*HI + bk*8 + m] = hn;
            }
        }
        gridbar(bar, ++tgt);
    }
}

// out[b,t,v] = h_seq[t,b,:] @ W_fc + b_fc  — MFMA (hi/lo bf16 split), one t per block
// grid (60 t fastest, 40 col-tiles): consecutive blocks share the Wfc col-tile in L2
__launch_bounds__(512, 1)
__global__ void k_logits(const float* __restrict__ h_seq, const float* __restrict__ Wfc,
                         const float* __restrict__ bfc, float* __restrict__ out){
    __shared__ __align__(16) ushort h_hi[16384], h_lo[16384];   // 32 rows x 512 bf16 x2
    int t = blockIdx.x, vt = blockIdx.y;
    int tid = threadIdx.x, lane = tid & 63, wave = tid >> 6;
    // stage h rows (t*32 .. t*32+31) as bf16 hi/lo, swizzled (same layout as scan)
    const float* hs = h_seq + (size_t)t*BB*HI;
    #pragma unroll
    for (int it = 0; it < 4; it++){
        int flat = (it*512 + tid)*8;
        int b = flat >> 9, k = flat & 511;
        float4 v0 = *(const float4*)(hs + flat);
        float4 v1 = *(const float4*)(hs + flat + 4);
        float fv[8] = {v0.x,v0.y,v0.z,v0.w,v1.x,v1.y,v1.z,v1.w};
        union { ushort u[8]; uint4 v; } ph, pl;
        #pragma unroll
        for (int j = 0; j < 8; j++){
            ushort hi = f2bf(fv[j]);
            ph.u[j] = hi;
            pl.u[j] = f2bf(fv[j] - bf2f(hi));
        }
        int di = (b*512 + k) ^ ((b&7)<<3);
        *(uint4*)&h_hi[di] = ph.v;
        *(uint4*)&h_lo[di] = pl.v;
    }
    __syncthreads();

    int m = lane & 15, kg = lane >> 4;
    int cb = vt*256 + wave*32;          // this wave's 32 cols
    // A-frag bases for both row groups (rows m and 16+m); xor identical ((16+m)&7==m&7)
    int a0 = m*512 + kg*8;
    int a1 = (16+m)*512 + kg*8;
    int axr = (m&7)<<3;
    float4v acc[2][2];
    acc[0][0]=(float4v){0,0,0,0}; acc[0][1]=(float4v){0,0,0,0};
    acc[1][0]=(float4v){0,0,0,0}; acc[1][1]=(float4v){0,0,0,0};
    const short8v bz = {0,0,0,0,0,0,0,0};

    for (int ks = 0; ks < 16; ks++){
        short8v ah0 = *(const short8v*)&h_hi[(a0 + ks*32) ^ axr];
        short8v al0 = *(const short8v*)&h_lo[(a0 + ks*32) ^ axr];
        short8v ah1 = *(const short8v*)&h_hi[(a1 + ks*32) ^ axr];
        short8v al1 = *(const short8v*)&h_lo[(a1 + ks*32) ^ axr];
        #pragma unroll
        for (int cj = 0; cj < 2; cj++){
            int v = cb + cj*16 + m;
            short8v bhi = bz, blo = bz;
            if (v < NV){
                int k0 = ks*32 + kg*8;
                const float* wp = Wfc + (size_t)k0*NV + v;
                float w[8];
                #pragma unroll
                for (int i = 0; i < 8; i++) w[i] = wp[(size_t)i*NV];
                union { ushort u[8]; short8v s; } bh, bl;
                #pragma unroll
                for (int i = 0; i < 8; i++){
                    ushort hi = f2bf(w[i]);
                    bh.u[i] = hi;
                    bl.u[i] = f2bf_trunc(w[i] - bf2f(hi));
                }
                bhi = bh.s; blo = bl.s;
            }
            acc[0][cj] = __builtin_amdgcn_mfma_f32_16x16x32_bf16(ah0, bhi, acc[0][cj], 0,0,0);
            acc[0][cj] = __builtin_amdgcn_mfma_f32_16x16x32_bf16(al0, bhi, acc[0][cj], 0,0,0);
            acc[0][cj] = __builtin_amdgcn_mfma_f32_16x16x32_bf16(ah0, blo, acc[0][cj], 0,0,0);
            acc[1][cj] = __builtin_amdgcn_mfma_f32_16x16x32_bf16(ah1, bhi, acc[1][cj], 0,0,0);
            acc[1][cj] = __builtin_amdgcn_mfma_f32_16x16x32_bf16(al1, bhi, acc[1][cj], 0,0,0);
            acc[1][cj] = __builtin_amdgcn_mfma_f32_16x16x32_bf16(ah1, blo, acc[1][cj], 0,0,0);
        }
    }
    #pragma unroll
    for (int cj = 0; cj < 2; cj++){
        int v = cb + cj*16 + m;
        if (v < NV){
            float bias = bfc[v];
            #pragma unroll
            for (int ri = 0; ri < 2; ri++){
                int b0 = ri*16 + kg*4;
                #pragma unroll
                for (int r = 0; r < 4; r++)
                    out[((size_t)(b0+r)*TT + t)*NV + v] = acc[ri][cj][r] + bias;
            }
        }
    }
}

extern "C" void kernel_launch(void* const* d_in, const int* in_sizes, int n_in,
                              void* d_out, int out_size, void* d_ws, size_t ws_size,
                              hipStream_t stream){
    const float* features = (const float*)d_in[0];
    const int*   captions = (const int*)d_in[1];
    const float* disease  = (const float*)d_in[2];
    const float* emb      = (const float*)d_in[3];
    const float* W_attn   = (const float*)d_in[4];
    const float* b_attn   = (const float*)d_in[5];
    const float* W_v      = (const float*)d_in[6];
    // d_in[7] = b_v : constant shift, cancels in softmax
    const float* W_dp1    = (const float*)d_in[8];
    const float* b_dp1    = (const float*)d_in[9];
    const float* W_dp2    = (const float*)d_in[10];
    const float* b_dp2    = (const float*)d_in[11];
    const float* W_de1    = (const float*)d_in[12];
    const float* b_de1    = (const float*)d_in[13];
    const float* W_de2    = (const float*)d_in[14];
    const float* b_de2    = (const float*)d_in[15];
    const float* W_ih     = (const float*)d_in[16];
    const float* W_hh     = (const float*)d_in[17];
    const float* b_ih     = (const float*)d_in[18];
    const float* b_hh     = (const float*)d_in[19];
    const float* W_fc     = (const float*)d_in[20];
    const float* b_fc     = (const float*)d_in[21];
    float* out = (float*)d_out;

    // ws: h_seq (read by k_logits while it writes d_out) + barrier state
    const size_t N_HSEQ = (size_t)TT*BB*HI;          // 983040
    float* h_seq = (float*)d_ws;
    int*   bar   = (int*)((char*)d_ws + N_HSEQ*sizeof(float));

    // all other scratch lives in d_out (never read by k_logits; k_logits
    // fully overwrites d_out last)
    const size_t N_FT   = (size_t)BB*NP*FE;          // 802816
    const size_t N_FP   = (size_t)BB*NP*HI;          // 802816
    const size_t N_FWC  = (size_t)BB*NP*G4;          // 3211264
    const size_t N_PREG = (size_t)BB*TT*G4;          // 3932160
    const size_t N_ABUF = (size_t)TT*BB*HI;          // 983040
    const size_t N_SC   = (size_t)TT*BB*NP;          // 94080
    float* fT     = out;
    float* f_proj = fT + N_FT;
    float* fWcP   = f_proj + N_FP;
    float* preGP  = fWcP + N_FWC;
    float* a_buf  = preGP + N_PREG;
    float* scores = a_buf + N_ABUF;
    float* disWih = scores + N_SC;
    float* daw    = disWih + (size_t)BB*G4;

    hipMemsetAsync(bar, 0, 1024, stream);
    k_transpose<<<dim3(8,BB),256,0,stream>>>(features, fT);
    k_disease<<<BB,256,0,stream>>>(disease, W_dp1,b_dp1,W_dp2,b_dp2,
                                   W_de1,b_de1,W_de2,b_de2,
                                   W_attn,b_attn, W_ih,b_ih,b_hh,
                                   daw, disWih);
    k_fproj<<<dim3(7,BB),256,0,stream>>>(fT, W_attn, f_proj);
    k_fwc<<<dim3(2,7,BB),256,0,stream>>>(fT, W_ih, fWcP);
    k_preg<<<dim3(4,120),256,0,stream>>>(captions, emb, W_ih, disWih, preGP);
    k_scan_coop<<<NBLK,512,0,stream>>>(f_proj, fWcP, preGP, daw,
                                       W_attn, W_hh, W_v,
                                       h_seq, a_buf, scores, bar);
    k_logits<<<dim3(TT,40),512,0,stream>>>(h_seq, W_fc, b_fc, out);
}

// Round 13
// 1667.767 us; speedup vs baseline: 1.4836x; 1.1003x over previous
//
#include <hip/hip_runtime.h>
#include <math.h>

#define BB 32      // batch
#define NP 49      // spatial positions 7*7
#define FE 512     // FEAT
#define HI 512     // HID
#define EM 512     // emb dim
#define TT 60      // timesteps
#define G4 2048    // 4*HID
#define NV 10000   // vocab
#define ND 14      // disease dim
#define NBLK 80    // cooperative scan blocks: 64 gate + 16 a

typedef __attribute__((ext_vector_type(8))) short short8v;
typedef __attribute__((ext_vector_type(4))) float float4v;

__device__ __forceinline__ float fsig(float x){ return 1.0f/(1.0f+__expf(-x)); }
__device__ __forceinline__ float ftanh(float x){
    x = fminf(fmaxf(x, -15.0f), 15.0f);
    float e = __expf(2.0f*x);
    return (e-1.0f)/(e+1.0f);
}
__device__ __forceinline__ ushort f2bf(float x){
    union { float f; unsigned u; } v; v.f = x;
    unsigned r = v.u + 0x7fff + ((v.u >> 16) & 1);
    return (ushort)(r >> 16);
}
__device__ __forceinline__ float bf2f(ushort h){
    union { float f; unsigned u; } v; v.u = ((unsigned)h) << 16;
    return v.f;
}
__device__ __forceinline__ ushort f2bf_trunc(float x){
    return (ushort)(__float_as_uint(x) >> 16);
}

// features (B,512,49) -> fT (B,49,512)
__global__ void k_transpose(const float* __restrict__ feat, float* __restrict__ fT){
    int b = blockIdx.y;
    int cb = blockIdx.x * 64;
    __shared__ float tile[64][NP+1];
    const float* src = feat + (size_t)b*FE*NP;
    for (int idx = threadIdx.x; idx < 64*NP; idx += 256){
        int cl = idx / NP, n = idx % NP;
        tile[cl][n] = src[(size_t)(cb+cl)*NP + n];
    }
    __syncthreads();
    float* dst = fT + (size_t)b*NP*FE;
    for (int idx = threadIdx.x; idx < 64*NP; idx += 256){
        int cl = idx % 64, n = idx / 64;
        dst[(size_t)n*FE + cb + cl] = tile[cl][n];
    }
}

// per-batch disease MLPs + folded projections
__global__ void k_disease(const float* __restrict__ dis,
                          const float* __restrict__ Wdp1, const float* __restrict__ bdp1,
                          const float* __restrict__ Wdp2, const float* __restrict__ bdp2,
                          const float* __restrict__ Wde1, const float* __restrict__ bde1,
                          const float* __restrict__ Wde2, const float* __restrict__ bde2,
                          const float* __restrict__ Wattn, const float* __restrict__ battn,
                          const float* __restrict__ Wih, const float* __restrict__ bih,
                          const float* __restrict__ bhh,
                          float* __restrict__ daw, float* __restrict__ disWih){
    int b = blockIdx.x;
    int tid = threadIdx.x;
    __shared__ float d[ND];
    __shared__ float hp[128], he[128];
    __shared__ float datt[HI];
    __shared__ float dctx[256];
    if (tid < ND) d[tid] = dis[b*ND + tid];
    __syncthreads();
    if (tid < 128){
        float accP = bdp1[tid], accE = bde1[tid];
        for (int k=0;k<ND;k++){ accP += d[k]*Wdp1[k*128+tid]; accE += d[k]*Wde1[k*128+tid]; }
        hp[tid] = fmaxf(accP, 0.f);
        he[tid] = fmaxf(accE, 0.f);
    }
    __syncthreads();
    for (int j = tid; j < HI; j += 256){
        float a = bdp2[j];
        for (int k=0;k<128;k++) a += hp[k]*Wdp2[k*HI+j];
        datt[j] = a;
    }
    if (tid < 256){
        float a = bde2[tid];
        for (int k=0;k<128;k++) a += he[k]*Wde2[k*256+tid];
        dctx[tid] = a;
    }
    __syncthreads();
    for (int j = tid; j < HI; j += 256){
        float a = battn[j];
        for (int k=0;k<HI;k++) a += datt[k]*Wattn[(size_t)(FE+k)*HI + j];
        daw[b*HI + j] = a;
    }
    for (int j = tid; j < G4; j += 256){
        float a = bih[j] + bhh[j];
        for (int k=0;k<256;k++) a += dctx[k]*Wih[(size_t)(EM+FE+k)*G4 + j];
        disWih[b*G4 + j] = a;
    }
}

// ---- shared MFMA-GEMM helpers (k_logits-verified pattern) ----
// stage 32 fp32 rows (512 K) -> bf16 hi/lo LDS, XOR-swizzled
__device__ __forceinline__ void stage_rows32(const float* __restrict__ src0, size_t ldsrc,
                                             const int* __restrict__ rowmap, // LDS, or null
                                             ushort* h_hi, ushort* h_lo, int tid){
    #pragma unroll
    for (int it = 0; it < 4; it++){
        int flat = (it*512 + tid)*8;
        int row = flat >> 9, k = flat & 511;
        const float* src = src0 + (rowmap ? (size_t)rowmap[row]*ldsrc : (size_t)row*ldsrc) + k;
        float4 v0 = *(const float4*)(src);
        float4 v1 = *(const float4*)(src + 4);
        float fv[8] = {v0.x,v0.y,v0.z,v0.w,v1.x,v1.y,v1.z,v1.w};
        union { ushort u[8]; uint4 v; } ph, pl;
        #pragma unroll
        for (int j = 0; j < 8; j++){
            ushort hi = f2bf(fv[j]);
            ph.u[j] = hi;
            pl.u[j] = f2bf_trunc(fv[j] - bf2f(hi));
        }
        int di = (row*512 + k) ^ ((row&7)<<3);
        *(uint4*)&h_hi[di] = ph.v;
        *(uint4*)&h_lo[di] = pl.v;
    }
}

// 32 rows x 32 cols (this wave) hi/lo MFMA accumulate; B from global, ld stride
__device__ __forceinline__ void mfma_32x32(const ushort* h_hi, const ushort* h_lo,
                                           const float* __restrict__ Wb, size_t ldB, int col0,
                                           int lane, float4v acc[2][2]){
    int m = lane & 15, kg = lane >> 4;
    int a0 = m*512 + kg*8;
    int a1 = (16+m)*512 + kg*8;
    int axr = (m&7)<<3;
    for (int ks = 0; ks < 16; ks++){
        short8v ah0 = *(const short8v*)&h_hi[(a0 + ks*32) ^ axr];
        short8v al0 = *(const short8v*)&h_lo[(a0 + ks*32) ^ axr];
        short8v ah1 = *(const short8v*)&h_hi[(a1 + ks*32) ^ axr];
        short8v al1 = *(const short8v*)&h_lo[(a1 + ks*32) ^ axr];
        #pragma unroll
        for (int cj = 0; cj < 2; cj++){
            int v = col0 + cj*16 + m;
            int k0 = ks*32 + kg*8;
            const float* wp = Wb + (size_t)k0*ldB + v;
            float w[8];
            #pragma unroll
            for (int i = 0; i < 8; i++) w[i] = wp[(size_t)i*ldB];
            union { ushort u[8]; short8v s; } bh, bl;
            #pragma unroll
            for (int i = 0; i < 8; i++){
                ushort hi = f2bf(w[i]);
                bh.u[i] = hi;
                bl.u[i] = f2bf_trunc(w[i] - bf2f(hi));
            }
            acc[0][cj] = __builtin_amdgcn_mfma_f32_16x16x32_bf16(ah0, bh.s, acc[0][cj], 0,0,0);
            acc[0][cj] = __builtin_amdgcn_mfma_f32_16x16x32_bf16(al0, bh.s, acc[0][cj], 0,0,0);
            acc[0][cj] = __builtin_amdgcn_mfma_f32_16x16x32_bf16(ah0, bl.s, acc[0][cj], 0,0,0);
            acc[1][cj] = __builtin_amdgcn_mfma_f32_16x16x32_bf16(ah1, bh.s, acc[1][cj], 0,0,0);
            acc[1][cj] = __builtin_amdgcn_mfma_f32_16x16x32_bf16(al1, bh.s, acc[1][cj], 0,0,0);
            acc[1][cj] = __builtin_amdgcn_mfma_f32_16x16x32_bf16(ah1, bl.s, acc[1][cj], 0,0,0);
        }
    }
}

// f_proj[r, col] = fT[r,:] @ Wattn[0:512, col]   (rows r = b*49+n)
__launch_bounds__(512, 1)
__global__ void k_fproj(const float* __restrict__ fT, const float* __restrict__ Wattn,
                        float* __restrict__ f_proj){
    __shared__ __align__(16) ushort h_hi[16384], h_lo[16384];
    int r0 = blockIdx.x*32, vt = blockIdx.y;
    int tid = threadIdx.x, lane = tid & 63, wave = tid >> 6;
    stage_rows32(fT + (size_t)r0*FE, FE, nullptr, h_hi, h_lo, tid);
    __syncthreads();
    int col0 = vt*256 + wave*32;
    float4v acc[2][2];
    acc[0][0]=(float4v){0,0,0,0}; acc[0][1]=(float4v){0,0,0,0};
    acc[1][0]=(float4v){0,0,0,0}; acc[1][1]=(float4v){0,0,0,0};
    mfma_32x32(h_hi, h_lo, Wattn, HI, col0, lane, acc);
    int m = lane & 15, kg = lane >> 4;
    #pragma unroll
    for (int cj = 0; cj < 2; cj++){
        int col = col0 + cj*16 + m;
        #pragma unroll
        for (int ri = 0; ri < 2; ri++){
            int arow0 = ri*16 + kg*4;
            #pragma unroll
            for (int r = 0; r < 4; r++)
                f_proj[(size_t)(r0 + arow0 + r)*HI + col] = acc[ri][cj][r];
        }
    }
}

// fWcP[blk][b][n][c=32] = fT[r,:] @ Wih[512:1024, gc]  (packed, r=b*49+n)
__launch_bounds__(512, 1)
__global__ void k_fwc(const float* __restrict__ fT, const float* __restrict__ Wih,
                      float* __restrict__ fWcP){
    __shared__ __align__(16) ushort h_hi[16384], h_lo[16384];
    int r0 = blockIdx.x*32, vt = blockIdx.y;
    int tid = threadIdx.x, lane = tid & 63, wave = tid >> 6;
    stage_rows32(fT + (size_t)r0*FE, FE, nullptr, h_hi, h_lo, tid);
    __syncthreads();
    int col0 = vt*256 + wave*32;
    float4v acc[2][2];
    acc[0][0]=(float4v){0,0,0,0}; acc[0][1]=(float4v){0,0,0,0};
    acc[1][0]=(float4v){0,0,0,0}; acc[1][1]=(float4v){0,0,0,0};
    mfma_32x32(h_hi, h_lo, Wih + (size_t)FE*G4, G4, col0, lane, acc);
    int m = lane & 15, kg = lane >> 4;
    #pragma unroll
    for (int cj = 0; cj < 2; cj++){
        int gc = col0 + cj*16 + m;
        int blk = (gc & 511) >> 3, m8 = gc & 7, g = gc >> 9;
        #pragma unroll
        for (int ri = 0; ri < 2; ri++){
            int arow0 = ri*16 + kg*4;
            #pragma unroll
            for (int r = 0; r < 4; r++){
                int R = r0 + arow0 + r;
                int b = R / 49, n = R - b*49;
                fWcP[(((size_t)blk*BB + b)*NP + n)*32 + m8*4 + g] = acc[ri][cj][r];
            }
        }
    }
}

// preGP[blk][t][b][c=32] = emb[captions[R],:] @ Wih[0:512, gc] + disWih[b,gc]  (R=b*60+t)
__launch_bounds__(512, 1)
__global__ void k_preg(const int* __restrict__ caps, const float* __restrict__ emb,
                       const float* __restrict__ Wih, const float* __restrict__ disWih,
                       float* __restrict__ preGP){
    __shared__ __align__(16) ushort h_hi[16384], h_lo[16384];
    __shared__ int bidx[32];
    int r0 = blockIdx.x*32, vt = blockIdx.y;
    int tid = threadIdx.x, lane = tid & 63, wave = tid >> 6;
    if (tid < 32) bidx[tid] = caps[r0 + tid];
    __syncthreads();
    stage_rows32(emb, EM, bidx, h_hi, h_lo, tid);
    __syncthreads();
    int col0 = vt*256 + wave*32;
    float4v acc[2][2];
    acc[0][0]=(float4v){0,0,0,0}; acc[0][1]=(float4v){0,0,0,0};
    acc[1][0]=(float4v){0,0,0,0}; acc[1][1]=(float4v){0,0,0,0};
    mfma_32x32(h_hi, h_lo, Wih, G4, col0, lane, acc);
    int m = lane & 15, kg = lane >> 4;
    #pragma unroll
    for (int cj = 0; cj < 2; cj++){
        int gc = col0 + cj*16 + m;
        int blk = (gc & 511) >> 3, m8 = gc & 7, g = gc >> 9;
        #pragma unroll
        for (int ri = 0; ri < 2; ri++){
            int arow0 = ri*16 + kg*4;
            #pragma unroll
            for (int r = 0; r < 4; r++){
                int R = r0 + arow0 + r;
                int b = R / 60, t = R - b*60;
                preGP[(((size_t)blk*TT + t)*BB + b)*32 + m8*4 + g] =
                    acc[ri][cj][r] + disWih[b*G4 + gc];
            }
        }
    }
}

// ---- store-arrive / checker-release grid barrier, release/relaxed form ----
__device__ __forceinline__ void gridbar(int* bar, int tgt){
    __syncthreads();
    if (threadIdx.x == 0)
        __hip_atomic_store(bar + blockIdx.x, tgt, __ATOMIC_RELEASE, __HIP_MEMORY_SCOPE_AGENT);
    if (blockIdx.x == 0 && threadIdx.x < 64){
        int l = threadIdx.x;
        for (;;){
            int v0 = __hip_atomic_load(bar + l, __ATOMIC_RELAXED, __HIP_MEMORY_SCOPE_AGENT);
            int v1 = (l < NBLK-64) ? __hip_atomic_load(bar + 64 + l, __ATOMIC_RELAXED, __HIP_MEMORY_SCOPE_AGENT) : tgt;
            if (__all(v0 >= tgt && v1 >= tgt)) break;
            __builtin_amdgcn_s_sleep(1);
        }
        if (l == 0)
            __hip_atomic_store(bar + 128, tgt, __ATOMIC_RELEASE, __HIP_MEMORY_SCOPE_AGENT);
    }
    if (threadIdx.x == 0){
        while (__hip_atomic_load(bar + 128, __ATOMIC_RELAXED, __HIP_MEMORY_SCOPE_AGENT) < tgt)
            __builtin_amdgcn_s_sleep(1);
    }
    __syncthreads();
}

// cooperative scan (R12, unchanged)
__launch_bounds__(512, 1)
__global__ void k_scan_coop(const float* __restrict__ f_proj, const float* __restrict__ fWcP,
                            const float* __restrict__ preGP, const float* __restrict__ daw,
                            const float* __restrict__ Wattn, const float* __restrict__ Whh,
                            const float* __restrict__ Wv,
                            float* __restrict__ h_seq, float* __restrict__ a_buf,
                            float* __restrict__ scores, int* __restrict__ bar){
    __shared__ __align__(16) ushort h_hi[16384], h_lo[16384];   // 64 KiB
    __shared__ __align__(16) ushort w_hi[16384], w_lo[16384];   // 64 KiB
    __shared__ float al[32*52];
    __shared__ float gbuf[32*33];
    __shared__ float daw_lds[32*32];
    __shared__ float gv[32*36];
    __shared__ float cst[256];
    __shared__ float wvl[512];
    int bk = blockIdx.x;
    int tid = threadIdx.x;
    int lane = tid & 63, wave = tid >> 6;
    bool isGate = bk < 64;

    {
        int k = tid;
        if (isGate){
            const float* wr = Whh + (size_t)k*G4 + bk*8;
            #pragma unroll
            for (int g = 0; g < 4; g++){
                float4 v0 = *(const float4*)(wr + g*512);
                float4 v1 = *(const float4*)(wr + g*512 + 4);
                float vv[8] = {v0.x,v0.y,v0.z,v0.w,v1.x,v1.y,v1.z,v1.w};
                #pragma unroll
                for (int u = 0; u < 8; u++){
                    int c = u*4 + g;
                    ushort hi = f2bf(vv[u]);
                    ushort lo = f2bf(vv[u] - bf2f(hi));
                    int idx = (c*512 + k) ^ ((c&7)<<3);
                    w_hi[idx] = hi; w_lo[idx] = lo;
                }
            }
        } else {
            const float* wr = Wattn + (size_t)(FE + k)*HI + (bk-64)*32;
            #pragma unroll
            for (int cq = 0; cq < 8; cq++){
                float4 v = *(const float4*)(wr + cq*4);
                float vv[4] = {v.x,v.y,v.z,v.w};
                #pragma unroll
                for (int q = 0; q < 4; q++){
                    int c = cq*4 + q;
                    ushort hi = f2bf(vv[q]);
                    ushort lo = f2bf(vv[q] - bf2f(hi));
                    int idx = (c*512 + k) ^ ((c&7)<<3);
                    w_hi[idx] = hi; w_lo[idx] = lo;
                }
            }
            for (int i = tid; i < 1024; i += 512){
                int b = i >> 5, c = i & 31;
                daw_lds[i] = daw[b*HI + (bk-64)*32 + c];
            }
        }
        if (tid < 256) cst[tid] = 0.f;
        wvl[tid] = Wv[tid];
    }
    __syncthreads();

    int tgt = 0;
    for (int t = 0; t < TT; t++){
        if (t == 0){
            uint4 z = make_uint4(0,0,0,0);
            #pragma unroll
            for (int it = 0; it < 4; it++){
                int flat = (it*512 + tid)*8;
                int b = flat >> 9, k = flat & 511;
                int di = (b*512 + k) ^ ((b&7)<<3);
                *(uint4*)&h_hi[di] = z;
                *(uint4*)&h_lo[di] = z;
            }
        } else {
            const float* hs = h_seq + (size_t)(t-1)*BB*HI;
            #pragma unroll
            for (int it = 0; it < 4; it++){
                int flat = (it*512 + tid)*8;
                int b = flat >> 9, k = flat & 511;
                float4 v0 = *(const float4*)(hs + flat);
                float4 v1 = *(const float4*)(hs + flat + 4);
                float fv[8] = {v0.x,v0.y,v0.z,v0.w,v1.x,v1.y,v1.z,v1.w};
                union { ushort u[8]; uint4 v; } ph, pl;
                #pragma unroll
                for (int j = 0; j < 8; j++){
                    ushort hi = f2bf(fv[j]);
                    ph.u[j] = hi;
                    pl.u[j] = f2bf(fv[j] - bf2f(hi));
                }
                int di = (b*512 + k) ^ ((b&7)<<3);
                *(uint4*)&h_hi[di] = ph.v;
                *(uint4*)&h_lo[di] = pl.v;
            }
        }
        __syncthreads();

        if (wave < 4){
            int rbase = (wave >> 1) * 16, cbase = (wave & 1) * 16;
            int m = lane & 15, kg = lane >> 4;
            int arow = rbase + m, bcol = cbase + m;
            int abase = arow*512 + kg*8, axr = (arow&7)<<3;
            int bbase = bcol*512 + kg*8, bxr = (bcol&7)<<3;
            float4v acc = {0.f,0.f,0.f,0.f};
            #pragma unroll
            for (int ks = 0; ks < 16; ks++){
                int ai = (abase + ks*32) ^ axr;
                int bi = (bbase + ks*32) ^ bxr;
                short8v ahi = *(const short8v*)&h_hi[ai];
                short8v alo = *(const short8v*)&h_lo[ai];
                short8v bhi = *(const short8v*)&w_hi[bi];
                short8v blo = *(const short8v*)&w_lo[bi];
                acc = __builtin_amdgcn_mfma_f32_16x16x32_bf16(ahi, bhi, acc, 0,0,0);
                acc = __builtin_amdgcn_mfma_f32_16x16x32_bf16(alo, bhi, acc, 0,0,0);
                acc = __builtin_amdgcn_mfma_f32_16x16x32_bf16(ahi, blo, acc, 0,0,0);
            }
            int ccol = cbase + (lane & 15);
            int crow0 = rbase + (lane >> 4)*4;
            if (isGate){
                #pragma unroll
                for (int r = 0; r < 4; r++)
                    gbuf[(crow0+r)*33 + ccol] = acc[r];
            } else {
                int cb = (bk-64)*32;
                float* ab = a_buf + (size_t)t*BB*HI;
                #pragma unroll
                for (int r = 0; r < 4; r++)
                    ab[(size_t)(crow0+r)*HI + cb + ccol] = acc[r] + daw_lds[(crow0+r)*32 + ccol];
            }
        }
        gridbar(bar, ++tgt);

        {
            int wid = tid >> 6, l = tid & 63;
            for (int p = bk + wid*NBLK; p < BB*NP; p += NBLK*8){
                int pb = p / NP, pn = p - pb*NP;
                const float* fpn = f_proj + ((size_t)pb*NP + pn)*HI;
                const float* at  = a_buf + ((size_t)t*BB + pb)*HI;
                int j = l*8;
                float4 f0 = *(const float4*)(fpn + j);
                float4 a0 = *(const float4*)(at + j);
                float4 f1 = *(const float4*)(fpn + j + 4);
                float4 a1 = *(const float4*)(at + j + 4);
                float s = wvl[j+0]*ftanh(f0.x + a0.x)
                        + wvl[j+1]*ftanh(f0.y + a0.y)
                        + wvl[j+2]*ftanh(f0.z + a0.z)
                        + wvl[j+3]*ftanh(f0.w + a0.w)
                        + wvl[j+4]*ftanh(f1.x + a1.x)
                        + wvl[j+5]*ftanh(f1.y + a1.y)
                        + wvl[j+6]*ftanh(f1.z + a1.z)
                        + wvl[j+7]*ftanh(f1.w + a1.w);
                #pragma unroll
                for (int off = 32; off; off >>= 1) s += __shfl_xor(s, off);
                if (l == 0) scores[t*(BB*NP) + p] = s;
            }
        }
        gridbar(bar, ++tgt);

        if (isGate){
            int hw = tid >> 5, l32 = tid & 31;
            #pragma unroll
            for (int rep = 0; rep < 2; rep++){
                int b = hw + rep*16;
                const float* sb = scores + t*(BB*NP) + b*NP;
                float s0 = sb[l32];
                float s1 = (l32 < 17) ? sb[32 + l32] : -1e30f;
                float m = fmaxf(s0, s1);
                #pragma unroll
                for (int off = 16; off; off >>= 1) m = fmaxf(m, __shfl_xor(m, off, 32));
                float e0 = __expf(s0 - m);
                float e1 = (l32 < 17) ? __expf(s1 - m) : 0.f;
                float sm = e0 + e1;
                #pragma unroll
                for (int off = 16; off; off >>= 1) sm += __shfl_xor(sm, off, 32);
                float inv = 1.f / sm;
                al[b*52 + l32] = e0*inv;
                if (l32 < 17) al[b*52 + 32 + l32] = e1*inv;
            }
            __syncthreads();
            {
                int b = tid >> 4, cp = tid & 15;
                float g0 = gbuf[b*33 + cp];
                float g1 = gbuf[b*33 + cp + 16];
                const float* pgp = preGP + (((size_t)bk*TT + t)*BB + b)*32;
                g0 += pgp[cp];
                g1 += pgp[cp + 16];
                const float* fw = fWcP + (((size_t)bk*BB + b)*NP)*32;
                for (int n = 0; n < NP; n++){
                    float av = al[b*52 + n];
                    g0 += av*fw[n*32 + cp];
                    g1 += av*fw[n*32 + cp + 16];
                }
                gv[b*36 + cp]      = g0;
                gv[b*36 + cp + 16] = g1;
            }
            __syncthreads();
            if (tid < 256){
                int b = tid >> 3, m = tid & 7;
                float gi = gv[b*36 + m*4 + 0];
                float gf = gv[b*36 + m*4 + 1];
                float gg = gv[b*36 + m*4 + 2];
                float go = gv[b*36 + m*4 + 3];
                float cn = fsig(gf)*cst[b*8 + m] + fsig(gi)*ftanh(gg);
                float hn = fsig(go)*ftanh(cn);
                cst[b*8 + m] = cn;
                h_seq[(size_t)t*BB*HI + b*HI + bk*8 + m] = hn;
            }
        }
        gridbar(bar, ++tgt);
    }
}

// out[b,t,v] = h_seq[t,b,:] @ W_fc + b_fc  — MFMA (hi/lo bf16 split), one t per block
__launch_bounds__(512, 1)
__global__ void k_logits(const float* __restrict__ h_seq, const float* __restrict__ Wfc,
                         const float* __restrict__ bfc, float* __restrict__ out){
    __shared__ __align__(16) ushort h_hi[16384], h_lo[16384];
    int t = blockIdx.x, vt = blockIdx.y;
    int tid = threadIdx.x, lane = tid & 63, wave = tid >> 6;
    stage_rows32(h_seq + (size_t)t*BB*HI, HI, nullptr, h_hi, h_lo, tid);
    __syncthreads();

    int m = lane & 15, kg = lane >> 4;
    int cb = vt*256 + wave*32;
    int a0 = m*512 + kg*8;
    int a1 = (16+m)*512 + kg*8;
    int axr = (m&7)<<3;
    float4v acc[2][2];
    acc[0][0]=(float4v){0,0,0,0}; acc[0][1]=(float4v){0,0,0,0};
    acc[1][0]=(float4v){0,0,0,0}; acc[1][1]=(float4v){0,0,0,0};
    const short8v bz = {0,0,0,0,0,0,0,0};

    for (int ks = 0; ks < 16; ks++){
        short8v ah0 = *(const short8v*)&h_hi[(a0 + ks*32) ^ axr];
        short8v al0 = *(const short8v*)&h_lo[(a0 + ks*32) ^ axr];
        short8v ah1 = *(const short8v*)&h_hi[(a1 + ks*32) ^ axr];
        short8v al1 = *(const short8v*)&h_lo[(a1 + ks*32) ^ axr];
        #pragma unroll
        for (int cj = 0; cj < 2; cj++){
            int v = cb + cj*16 + m;
            short8v bhi = bz, blo = bz;
            if (v < NV){
                int k0 = ks*32 + kg*8;
                const float* wp = Wfc + (size_t)k0*NV + v;
                float w[8];
                #pragma unroll
                for (int i = 0; i < 8; i++) w[i] = wp[(size_t)i*NV];
                union { ushort u[8]; short8v s; } bh, bl;
                #pragma unroll
                for (int i = 0; i < 8; i++){
                    ushort hi = f2bf(w[i]);
                    bh.u[i] = hi;
                    bl.u[i] = f2bf_trunc(w[i] - bf2f(hi));
                }
                bhi = bh.s; blo = bl.s;
            }
            acc[0][cj] = __builtin_amdgcn_mfma_f32_16x16x32_bf16(ah0, bhi, acc[0][cj], 0,0,0);
            acc[0][cj] = __builtin_amdgcn_mfma_f32_16x16x32_bf16(al0, bhi, acc[0][cj], 0,0,0);
            acc[0][cj] = __builtin_amdgcn_mfma_f32_16x16x32_bf16(ah0, blo, acc[0][cj], 0,0,0);
            acc[1][cj] = __builtin_amdgcn_mfma_f32_16x16x32_bf16(ah1, bhi, acc[1][cj], 0,0,0);
            acc[1][cj] = __builtin_amdgcn_mfma_f32_16x16x32_bf16(al1, bhi, acc[1][cj], 0,0,0);
            acc[1][cj] = __builtin_amdgcn_mfma_f32_16x16x32_bf16(ah1, blo, acc[1][cj], 0,0,0);
        }
    }
    #pragma unroll
    for (int cj = 0; cj < 2; cj++){
        int v = cb + cj*16 + m;
        if (v < NV){
            float bias = bfc[v];
            #pragma unroll
            for (int ri = 0; ri < 2; ri++){
                int b0 = ri*16 + kg*4;
                #pragma unroll
                for (int r = 0; r < 4; r++)
                    out[((size_t)(b0+r)*TT + t)*NV + v] = acc[ri][cj][r] + bias;
            }
        }
    }
}

extern "C" void kernel_launch(void* const* d_in, const int* in_sizes, int n_in,
                              void* d_out, int out_size, void* d_ws, size_t ws_size,
                              hipStream_t stream){
    const float* features = (const float*)d_in[0];
    const int*   captions = (const int*)d_in[1];
    const float* disease  = (const float*)d_in[2];
    const float* emb      = (const float*)d_in[3];
    const float* W_attn   = (const float*)d_in[4];
    const float* b_attn   = (const float*)d_in[5];
    const float* W_v      = (const float*)d_in[6];
    // d_in[7] = b_v : constant shift, cancels in softmax
    const float* W_dp1    = (const float*)d_in[8];
    const float* b_dp1    = (const float*)d_in[9];
    const float* W_dp2    = (const float*)d_in[10];
    const float* b_dp2    = (const float*)d_in[11];
    const float* W_de1    = (const float*)d_in[12];
    const float* b_de1    = (const float*)d_in[13];
    const float* W_de2    = (const float*)d_in[14];
    const float* b_de2    = (const float*)d_in[15];
    const float* W_ih     = (const float*)d_in[16];
    const float* W_hh     = (const float*)d_in[17];
    const float* b_ih     = (const float*)d_in[18];
    const float* b_hh     = (const float*)d_in[19];
    const float* W_fc     = (const float*)d_in[20];
    const float* b_fc     = (const float*)d_in[21];
    float* out = (float*)d_out;

    // ws: h_seq (read by k_logits while it writes d_out) + barrier state
    const size_t N_HSEQ = (size_t)TT*BB*HI;          // 983040
    float* h_seq = (float*)d_ws;
    int*   bar   = (int*)((char*)d_ws + N_HSEQ*sizeof(float));

    // all other scratch lives in d_out (never read by k_logits; k_logits
    // fully overwrites d_out last)
    const size_t N_FT   = (size_t)BB*NP*FE;          // 802816
    const size_t N_FP   = (size_t)BB*NP*HI;          // 802816
    const size_t N_FWC  = (size_t)BB*NP*G4;          // 3211264
    const size_t N_PREG = (size_t)BB*TT*G4;          // 3932160
    const size_t N_ABUF = (size_t)TT*BB*HI;          // 983040
    const size_t N_SC   = (size_t)TT*BB*NP;          // 94080
    float* fT     = out;
    float* f_proj = fT + N_FT;
    float* fWcP   = f_proj + N_FP;
    float* preGP  = fWcP + N_FWC;
    float* a_buf  = preGP + N_PREG;
    float* scores = a_buf + N_ABUF;
    float* disWih = scores + N_SC;
    float* daw    = disWih + (size_t)BB*G4;

    hipMemsetAsync(bar, 0, 1024, stream);
    k_transpose<<<dim3(8,BB),256,0,stream>>>(features, fT);
    k_disease<<<BB,256,0,stream>>>(disease, W_dp1,b_dp1,W_dp2,b_dp2,
                                   W_de1,b_de1,W_de2,b_de2,
                                   W_attn,b_attn, W_ih,b_ih,b_hh,
                                   daw, disWih);
    k_fproj<<<dim3(49,2),512,0,stream>>>(fT, W_attn, f_proj);
    k_fwc<<<dim3(49,8),512,0,stream>>>(fT, W_ih, fWcP);
    k_preg<<<dim3(60,8),512,0,stream>>>(captions, emb, W_ih, disWih, preGP);
    k_scan_coop<<<NBLK,512,0,stream>>>(f_proj, fWcP, preGP, daw,
                                       W_attn, W_hh, W_v,
                                       h_seq, a_buf, scores, bar);
    k_logits<<<dim3(TT,40),512,0,stream>>>(h_seq, W_fc, b_fc, out);
}